// Round 1
// baseline (779.165 us; speedup 1.0000x reference)
//
#include <hip/hip_runtime.h>
#include <hip/hip_bf16.h>
#include <math.h>

#define B_  16
#define N_  256
#define D_  1024
#define H_  8
#define DK_ 128

// ---------------------------------------------------------------------------
// SGEMM: out = A[M,K] @ W[K,N] + bias[N]
// permute==0: out row-major [M,N]
// permute==1: out scattered to [B, H, N_, DK_] layout (qkv projection)
// 64x64 tile, BK=16, 256 threads, 4x4 per thread, fp32.
// ---------------------------------------------------------------------------
__global__ __launch_bounds__(256)
void sgemm_bias_kernel(const float* __restrict__ A, const float* __restrict__ W,
                       const float* __restrict__ bias, float* __restrict__ out,
                       int M, int N, int K, int permute)
{
    __shared__ __align__(16) float As[16][68];  // transposed A tile [k][m], pad 68
    __shared__ __align__(16) float Bs[16][64];  // B tile [k][n]

    const int tid = threadIdx.x;
    const int tx = tid & 15;   // output col quad
    const int ty = tid >> 4;   // output row quad
    const int m0 = blockIdx.y * 64;
    const int n0 = blockIdx.x * 64;

    const int la_row = tid >> 2;        // 0..63
    const int la_k   = (tid & 3) * 4;   // 0,4,8,12
    const int lb_k   = tid >> 4;        // 0..15
    const int lb_col = (tid & 15) * 4;  // 0..60

    float acc[4][4] = {};

    for (int k0 = 0; k0 < K; k0 += 16) {
        const float4 av = *(const float4*)&A[(size_t)(m0 + la_row) * K + (k0 + la_k)];
        const float4 bv = *(const float4*)&W[(size_t)(k0 + lb_k) * N + (n0 + lb_col)];
        __syncthreads();
        As[la_k + 0][la_row] = av.x;
        As[la_k + 1][la_row] = av.y;
        As[la_k + 2][la_row] = av.z;
        As[la_k + 3][la_row] = av.w;
        *(float4*)&Bs[lb_k][lb_col] = bv;
        __syncthreads();
#pragma unroll
        for (int kk = 0; kk < 16; ++kk) {
            const float4 a4 = *(const float4*)&As[kk][ty * 4];
            const float4 b4 = *(const float4*)&Bs[kk][tx * 4];
            const float ar[4] = {a4.x, a4.y, a4.z, a4.w};
            const float br[4] = {b4.x, b4.y, b4.z, b4.w};
#pragma unroll
            for (int i = 0; i < 4; ++i)
#pragma unroll
                for (int j = 0; j < 4; ++j)
                    acc[i][j] = fmaf(ar[i], br[j], acc[i][j]);
        }
    }

    const int c0 = n0 + tx * 4;
    const float4 bb = *(const float4*)&bias[c0];
    const float badd[4] = {bb.x, bb.y, bb.z, bb.w};

    if (!permute) {
#pragma unroll
        for (int i = 0; i < 4; ++i) {
            const int m = m0 + ty * 4 + i;
            float4 o;
            o.x = acc[i][0] + badd[0];
            o.y = acc[i][1] + badd[1];
            o.z = acc[i][2] + badd[2];
            o.w = acc[i][3] + badd[3];
            *(float4*)&out[(size_t)m * N + c0] = o;
        }
    } else {
        // col c -> head h = c>>7, d = c&127 (c0 is a multiple of 4, block of 4
        // never crosses a 128 boundary)
        const int h  = c0 >> 7;
        const int d0 = c0 & 127;
#pragma unroll
        for (int i = 0; i < 4; ++i) {
            const int m = m0 + ty * 4 + i;
            const int b = m >> 8;     // token row -> batch
            const int n = m & 255;    // token within batch
            float4 o;
            o.x = acc[i][0] + badd[0];
            o.y = acc[i][1] + badd[1];
            o.z = acc[i][2] + badd[2];
            o.w = acc[i][3] + badd[3];
            *(float4*)&out[(((size_t)b * H_ + h) * N_ + n) * DK_ + d0] = o;
        }
    }
}

// ---------------------------------------------------------------------------
// Fused box relational embedding -> per-head Linear(64->1) -> relu -> log.
// Writes log-bias [B, H, N, N]. Block = (b, i); thread = j.
// Never materializes the [B,N,N,64] embedding.
// ---------------------------------------------------------------------------
__global__ __launch_bounds__(256)
void boxbias_kernel(const float* __restrict__ fg, const float* __restrict__ Wg,
                    const float* __restrict__ bg, float* __restrict__ lb)
{
    __shared__ float sWg[512];
    __shared__ float sbg[8];
    const int tid = threadIdx.x;
    const int b = blockIdx.x >> 8;
    const int i = blockIdx.x & 255;

    sWg[tid] = Wg[tid];
    sWg[tid + 256] = Wg[tid + 256];
    if (tid < 8) sbg[tid] = bg[tid];

    // box i (row box) params — uniform per block
    const float4 bi = *(const float4*)&fg[(size_t)(b * N_ + i) * 4];
    const float cxi = 0.5f * (bi.x + bi.z);
    const float cyi = 0.5f * (bi.y + bi.w);
    const float wi  = bi.z - bi.x + 1.0f;
    const float hi  = bi.w - bi.y + 1.0f;

    const int j = tid;
    const float4 bj = *(const float4*)&fg[(size_t)(b * N_ + j) * 4];
    const float cxj = 0.5f * (bj.x + bj.z);
    const float cyj = 0.5f * (bj.y + bj.w);
    const float wj  = bj.z - bj.x + 1.0f;
    const float hj  = bj.w - bj.y + 1.0f;

    // 100 * pos (fold the 100x in before the dim_mat multiply)
    const float pos[4] = {
        logf(fmaxf(fabsf((cxi - cxj) / wi), 1e-3f)) * 100.0f,
        logf(fmaxf(fabsf((cyi - cyj) / hi), 1e-3f)) * 100.0f,
        logf(wi / wj) * 100.0f,
        logf(hi / hj) * 100.0f
    };
    // dim_mat[q] = 1000^(-q/8)
    const float dim[8] = {1.0f, 0.421696503f, 0.177827941f, 0.0749894209f,
                          0.0316227766f, 0.0133352143f, 0.00562341325f, 0.00237137371f};

    float sv[32], cv[32];
#pragma unroll
    for (int p = 0; p < 4; ++p)
#pragma unroll
        for (int q = 0; q < 8; ++q)
            __sincosf(pos[p] * dim[q], &sv[p * 8 + q], &cv[p * 8 + q]);

    __syncthreads();
#pragma unroll
    for (int h = 0; h < 8; ++h) {
        float acc = sbg[h];
        const float* wrow = &sWg[h * 64];
#pragma unroll
        for (int g = 0; g < 32; ++g)
            acc = fmaf(sv[g], wrow[g], fmaf(cv[g], wrow[32 + g], acc));
        const float rel = fmaxf(acc, 0.0f);
        lb[(((size_t)b * H_ + h) * N_ + i) * N_ + j] = logf(fmaxf(rel, 1e-6f));
    }
}

// ---------------------------------------------------------------------------
// Attention: per block = (b, h, 32-query tile).
// scores = qk^T/sqrt(dk) + logbias; softmax; out = attn @ v (written in
// [B, N, H, DK] layout so the output GEMM reads it row-major).
// ---------------------------------------------------------------------------
__global__ __launch_bounds__(256)
void attn_kernel(const float* __restrict__ qp, const float* __restrict__ kp,
                 const float* __restrict__ vp, const float* __restrict__ lb,
                 float* __restrict__ ao)
{
    __shared__ __align__(16) float qs[32][132];
    __shared__ __align__(16) float kv[32][132];
    __shared__ __align__(16) float s[32][264];

    const int tid = threadIdx.x;
    const int bh = blockIdx.x >> 3;   // b*8 + h
    const int qt = blockIdx.x & 7;
    const int b = bh >> 3;
    const int h = bh & 7;
    const int q0 = qt * 32;

    const int qi = tid >> 3;  // 0..31 query row within tile
    const int lc = tid & 7;   // 0..7 lane-col

    // stage q tile [32][128]
    {
        const float* src = qp + ((size_t)bh * N_ + q0) * DK_;
#pragma unroll
        for (int it = 0; it < 4; ++it) {
            const int fi = it * 256 + tid;
            const int r = fi >> 5;
            const int c4 = (fi & 31) << 2;
            *(float4*)&qs[r][c4] = *(const float4*)&src[(size_t)r * DK_ + c4];
        }
    }

    const float scale = 0.08838834764831845f;  // 1/sqrt(128)
    const size_t brow = ((size_t)(b * H_ + h) * N_ + (q0 + qi)) * N_;

    // ---- scores ----
    for (int kt = 0; kt < 8; ++kt) {
        __syncthreads();
        {
            const float* src = kp + ((size_t)bh * N_ + kt * 32) * DK_;
#pragma unroll
            for (int it = 0; it < 4; ++it) {
                const int fi = it * 256 + tid;
                const int r = fi >> 5;
                const int c4 = (fi & 31) << 2;
                *(float4*)&kv[r][c4] = *(const float4*)&src[(size_t)r * DK_ + c4];
            }
        }
        __syncthreads();
        float a0 = 0.f, a1 = 0.f, a2 = 0.f, a3 = 0.f;
#pragma unroll 4
        for (int d = 0; d < DK_; d += 4) {
            const float4 qv = *(const float4*)&qs[qi][d];
            const float4 k0 = *(const float4*)&kv[lc][d];
            const float4 k1 = *(const float4*)&kv[lc + 8][d];
            const float4 k2 = *(const float4*)&kv[lc + 16][d];
            const float4 k3 = *(const float4*)&kv[lc + 24][d];
            a0 = fmaf(qv.x, k0.x, fmaf(qv.y, k0.y, fmaf(qv.z, k0.z, fmaf(qv.w, k0.w, a0))));
            a1 = fmaf(qv.x, k1.x, fmaf(qv.y, k1.y, fmaf(qv.z, k1.z, fmaf(qv.w, k1.w, a1))));
            a2 = fmaf(qv.x, k2.x, fmaf(qv.y, k2.y, fmaf(qv.z, k2.z, fmaf(qv.w, k2.w, a2))));
            a3 = fmaf(qv.x, k3.x, fmaf(qv.y, k3.y, fmaf(qv.z, k3.z, fmaf(qv.w, k3.w, a3))));
        }
        const int jb = kt * 32;
        s[qi][jb + lc]      = fmaf(a0, scale, lb[brow + jb + lc]);
        s[qi][jb + lc + 8]  = fmaf(a1, scale, lb[brow + jb + lc + 8]);
        s[qi][jb + lc + 16] = fmaf(a2, scale, lb[brow + jb + lc + 16]);
        s[qi][jb + lc + 24] = fmaf(a3, scale, lb[brow + jb + lc + 24]);
    }
    __syncthreads();

    // ---- softmax: 8 threads per row, thread covers cols lc + 8*cc ----
    float mx = -INFINITY;
#pragma unroll 8
    for (int cc = 0; cc < 32; ++cc)
        mx = fmaxf(mx, s[qi][lc + 8 * cc]);
    mx = fmaxf(mx, __shfl_xor(mx, 1));
    mx = fmaxf(mx, __shfl_xor(mx, 2));
    mx = fmaxf(mx, __shfl_xor(mx, 4));
    float sum = 0.f;
#pragma unroll 8
    for (int cc = 0; cc < 32; ++cc) {
        const float e = __expf(s[qi][lc + 8 * cc] - mx);
        s[qi][lc + 8 * cc] = e;
        sum += e;
    }
    sum += __shfl_xor(sum, 1);
    sum += __shfl_xor(sum, 2);
    sum += __shfl_xor(sum, 4);
    const float inv = 1.0f / sum;

    // ---- PV: thread owns d = lc*4 + r*32 + (0..3), r=0..3 ----
    float4 o[4] = {};
    for (int vt = 0; vt < 8; ++vt) {
        __syncthreads();
        {
            const float* src = vp + ((size_t)bh * N_ + vt * 32) * DK_;
#pragma unroll
            for (int it = 0; it < 4; ++it) {
                const int fi = it * 256 + tid;
                const int r = fi >> 5;
                const int c4 = (fi & 31) << 2;
                *(float4*)&kv[r][c4] = *(const float4*)&src[(size_t)r * DK_ + c4];
            }
        }
        __syncthreads();
        const int jb = vt * 32;
        for (int j = 0; j < 32; ++j) {
            const float p = s[qi][jb + j];
            const float* vr = &kv[j][lc * 4];
            const float4 v0 = *(const float4*)&vr[0];
            const float4 v1 = *(const float4*)&vr[32];
            const float4 v2 = *(const float4*)&vr[64];
            const float4 v3 = *(const float4*)&vr[96];
            o[0].x = fmaf(p, v0.x, o[0].x); o[0].y = fmaf(p, v0.y, o[0].y);
            o[0].z = fmaf(p, v0.z, o[0].z); o[0].w = fmaf(p, v0.w, o[0].w);
            o[1].x = fmaf(p, v1.x, o[1].x); o[1].y = fmaf(p, v1.y, o[1].y);
            o[1].z = fmaf(p, v1.z, o[1].z); o[1].w = fmaf(p, v1.w, o[1].w);
            o[2].x = fmaf(p, v2.x, o[2].x); o[2].y = fmaf(p, v2.y, o[2].y);
            o[2].z = fmaf(p, v2.z, o[2].z); o[2].w = fmaf(p, v2.w, o[2].w);
            o[3].x = fmaf(p, v3.x, o[3].x); o[3].y = fmaf(p, v3.y, o[3].y);
            o[3].z = fmaf(p, v3.z, o[3].z); o[3].w = fmaf(p, v3.w, o[3].w);
        }
    }
    // store to [B, N, H, DK] so the output GEMM reads row-major [M=4096, 1024]
    float* dst = ao + (((size_t)b * N_ + (q0 + qi)) * H_ + h) * DK_ + lc * 4;
#pragma unroll
    for (int r = 0; r < 4; ++r) {
        float4 ov;
        ov.x = o[r].x * inv; ov.y = o[r].y * inv;
        ov.z = o[r].z * inv; ov.w = o[r].w * inv;
        *(float4*)&dst[r * 32] = ov;
    }
}

// ---------------------------------------------------------------------------
// Workspace layout (floats):
//   qp [B,H,N,DK]  4194304
//   kp             4194304
//   vp             4194304
//   lb [B,H,N,N]   8388608
//   ao [B,N,D]     4194304
// total 25165824 floats = 96 MiB
// ---------------------------------------------------------------------------
extern "C" void kernel_launch(void* const* d_in, const int* in_sizes, int n_in,
                              void* d_out, int out_size, void* d_ws, size_t ws_size,
                              hipStream_t stream)
{
    const float* xq = (const float*)d_in[0];
    const float* xk = (const float*)d_in[1];
    const float* xv = (const float*)d_in[2];
    const float* fg = (const float*)d_in[3];
    const float* Wq = (const float*)d_in[4];
    const float* bq = (const float*)d_in[5];
    const float* Wk = (const float*)d_in[6];
    const float* bk = (const float*)d_in[7];
    const float* Wv = (const float*)d_in[8];
    const float* bv = (const float*)d_in[9];
    const float* Wg = (const float*)d_in[10];
    const float* bg = (const float*)d_in[11];
    const float* Wo = (const float*)d_in[12];
    const float* bo = (const float*)d_in[13];

    float* ws = (float*)d_ws;
    const size_t Q = (size_t)B_ * H_ * N_ * DK_;       // 4194304
    float* qp = ws;
    float* kp = ws + Q;
    float* vp = ws + 2 * Q;
    float* lb = ws + 3 * Q;                             // 8388608 floats
    float* ao = ws + 3 * Q + (size_t)B_ * H_ * N_ * N_;

    const int M = B_ * N_;   // 4096
    dim3 gemm_grid(D_ / 64, M / 64);   // (16, 64)

    sgemm_bias_kernel<<<gemm_grid, 256, 0, stream>>>(xq, Wq, bq, qp, M, D_, D_, 1);
    sgemm_bias_kernel<<<gemm_grid, 256, 0, stream>>>(xk, Wk, bk, kp, M, D_, D_, 1);
    sgemm_bias_kernel<<<gemm_grid, 256, 0, stream>>>(xv, Wv, bv, vp, M, D_, D_, 1);

    boxbias_kernel<<<B_ * N_, 256, 0, stream>>>(fg, Wg, bg, lb);

    attn_kernel<<<B_ * H_ * (N_ / 32), 256, 0, stream>>>(qp, kp, vp, lb, ao);

    sgemm_bias_kernel<<<gemm_grid, 256, 0, stream>>>(ao, Wo, bo, (float*)d_out, M, D_, D_, 0);
}

// Round 2
// 154.605 us; speedup vs baseline: 5.0397x; 5.0397x over previous
//
#include <hip/hip_runtime.h>
#include <hip/hip_bf16.h>
#include <math.h>

#define B_  16
#define N_  256
#define D_  1024
#define H_  8
#define DK_ 128

typedef unsigned short u16;
typedef __attribute__((ext_vector_type(8))) short s8v;   // 8 bf16 (4 VGPRs) MFMA A/B frag
typedef __attribute__((ext_vector_type(4))) float f4v;   // MFMA C/D frag

__device__ __forceinline__ u16 f2b(float x) {
    union { float f; unsigned u; } v; v.f = x;
    unsigned r = v.u + 0x7fffu + ((v.u >> 16) & 1u);   // RNE
    return (u16)(r >> 16);
}

__device__ __forceinline__ void gload16(void* lds, const void* g) {
    __builtin_amdgcn_global_load_lds(
        (const __attribute__((address_space(1))) void*)g,
        (__attribute__((address_space(3))) void*)lds, 16, 0, 0);
}

// ---------------------------------------------------------------------------
// fp32 -> bf16 elementwise convert (8 elems/thread)
// ---------------------------------------------------------------------------
__global__ __launch_bounds__(256)
void cvt_kernel(const float* __restrict__ in, u16* __restrict__ out, int n8)
{
    const int i = blockIdx.x * 256 + threadIdx.x;
    if (i >= n8) return;
    const float4 a = ((const float4*)in)[2 * i];
    const float4 b = ((const float4*)in)[2 * i + 1];
    union { u16 s[8]; uint4 v; } o;
    o.s[0] = f2b(a.x); o.s[1] = f2b(a.y); o.s[2] = f2b(a.z); o.s[3] = f2b(a.w);
    o.s[4] = f2b(b.x); o.s[5] = f2b(b.y); o.s[6] = f2b(b.z); o.s[7] = f2b(b.w);
    ((uint4*)out)[i] = o.v;
}

// ---------------------------------------------------------------------------
// Weight convert + transpose: W[K=1024][N=1024] fp32 -> Wt[N][K] bf16.
// z selects which of the 4 weights.
// ---------------------------------------------------------------------------
__global__ __launch_bounds__(256)
void cvtT_kernel(const float* __restrict__ W0, const float* __restrict__ W1,
                 const float* __restrict__ W2, const float* __restrict__ W3,
                 u16* __restrict__ out)
{
    const float* W = (blockIdx.z == 0) ? W0 : (blockIdx.z == 1) ? W1 :
                     (blockIdx.z == 2) ? W2 : W3;
    u16* o = out + (size_t)blockIdx.z * (D_ * D_);
    __shared__ float t[32][33];
    const int k0 = blockIdx.x * 32, n0 = blockIdx.y * 32;
    const int c = threadIdx.x & 31, r8 = threadIdx.x >> 5;
#pragma unroll
    for (int rr = 0; rr < 4; ++rr)
        t[r8 + rr * 8][c] = W[(size_t)(k0 + r8 + rr * 8) * D_ + n0 + c];
    __syncthreads();
#pragma unroll
    for (int rr = 0; rr < 4; ++rr)
        o[(size_t)(n0 + r8 + rr * 8) * D_ + k0 + c] = f2b(t[c][r8 + rr * 8]);
}

// ---------------------------------------------------------------------------
// bf16 MFMA GEMM: out = A[M=4096,K=1024] @ Wt[N,K]^T + bias
// tile 64(M) x 128(N), BK=32, 256 thr = 4 waves (2x2), 2x4 16x16 frags/wave.
// mode 0: fp32 out [M,N].  mode 1: bf16 out scattered to [B,H,N_,DK_].
// blockIdx.z selects A / Wt / bias / out slice (batched qkv).
// ---------------------------------------------------------------------------
__global__ __launch_bounds__(256)
void gemm_kernel(const u16* __restrict__ Ab, const u16* __restrict__ Wtb,
                 const float* __restrict__ b0, const float* __restrict__ b1,
                 const float* __restrict__ b2, void* __restrict__ outb, int mode)
{
    __shared__ __align__(16) u16 As[64][32];    // 4 KB, linear for global_load_lds
    __shared__ __align__(16) u16 Bs[128][32];   // 8 KB

    const int z = blockIdx.z;
    const u16* A  = Ab  + (size_t)z * (4096u * 1024u);
    const u16* Wt = Wtb + (size_t)z * (1024u * 1024u);
    const float* bias = (z == 0) ? b0 : (z == 1) ? b1 : b2;

    const int tid  = threadIdx.x;
    const int lane = tid & 63;
    const int w    = tid >> 6;
    const int l15  = lane & 15;
    const int l4   = lane >> 4;
    const int r2   = w >> 1;          // wave row block (0..1) of 32 rows
    const int c2   = w & 1;           // wave col block (0..1) of 64 cols
    const int m0   = blockIdx.y * 64;
    const int n0   = blockIdx.x * 128;

    // staging thread maps (LDS dest = wave base + lane*16, linear)
    const int arow = w * 16 + (lane >> 2);
    const int acol = (lane & 3) * 8;
    const int brow0 = w * 32 + (lane >> 2);
    const int brow1 = brow0 + 16;

    f4v acc[2][4] = {};

    for (int kt = 0; kt < 32; ++kt) {
        const int k0 = kt * 32;
        __syncthreads();   // previous compute done before overwrite
        gload16(&As[arow][acol],  A  + (size_t)(m0 + arow) * 1024 + k0 + acol);
        gload16(&Bs[brow0][acol], Wt + (size_t)(n0 + brow0) * 1024 + k0 + acol);
        gload16(&Bs[brow1][acol], Wt + (size_t)(n0 + brow1) * 1024 + k0 + acol);
        __syncthreads();   // compiler drains vmcnt before s_barrier

        s8v af[2], bf[4];
#pragma unroll
        for (int mf = 0; mf < 2; ++mf)
            af[mf] = *(const s8v*)&As[r2 * 32 + mf * 16 + l15][l4 * 8];
#pragma unroll
        for (int nf = 0; nf < 4; ++nf)
            bf[nf] = *(const s8v*)&Bs[c2 * 64 + nf * 16 + l15][l4 * 8];
#pragma unroll
        for (int mf = 0; mf < 2; ++mf)
#pragma unroll
            for (int nf = 0; nf < 4; ++nf)
                acc[mf][nf] = __builtin_amdgcn_mfma_f32_16x16x32_bf16(
                    af[mf], bf[nf], acc[mf][nf], 0, 0, 0);
    }

    // epilogue: C/D layout col = lane&15, row = (lane>>4)*4 + reg
#pragma unroll
    for (int mf = 0; mf < 2; ++mf) {
#pragma unroll
        for (int nf = 0; nf < 4; ++nf) {
            const int n = n0 + c2 * 64 + nf * 16 + l15;
            const float bb = bias[n];
#pragma unroll
            for (int reg = 0; reg < 4; ++reg) {
                const int m = m0 + r2 * 32 + mf * 16 + l4 * 4 + reg;
                const float val = acc[mf][nf][reg] + bb;
                if (mode == 0) {
                    ((float*)outb)[(size_t)m * 1024 + n] = val;
                } else {
                    const int b = m >> 8, tok = m & 255;
                    const int h = n >> 7, d = n & 127;
                    ((u16*)outb)[(size_t)z * (4096u * 1024u) +
                                 (((size_t)b * H_ + h) * N_ + tok) * DK_ + d] = f2b(val);
                }
            }
        }
    }
}

// ---------------------------------------------------------------------------
// Fused box relational embedding -> per-head Linear(64->1) -> relu -> log.
// ---------------------------------------------------------------------------
__global__ __launch_bounds__(256)
void boxbias_kernel(const float* __restrict__ fg, const float* __restrict__ Wg,
                    const float* __restrict__ bg, float* __restrict__ lb)
{
    __shared__ float sWg[512];
    __shared__ float sbg[8];
    const int tid = threadIdx.x;
    const int b = blockIdx.x >> 8;
    const int i = blockIdx.x & 255;

    sWg[tid] = Wg[tid];
    sWg[tid + 256] = Wg[tid + 256];
    if (tid < 8) sbg[tid] = bg[tid];

    const float4 bi = *(const float4*)&fg[(size_t)(b * N_ + i) * 4];
    const float cxi = 0.5f * (bi.x + bi.z);
    const float cyi = 0.5f * (bi.y + bi.w);
    const float wi  = bi.z - bi.x + 1.0f;
    const float hi  = bi.w - bi.y + 1.0f;

    const int j = tid;
    const float4 bj = *(const float4*)&fg[(size_t)(b * N_ + j) * 4];
    const float cxj = 0.5f * (bj.x + bj.z);
    const float cyj = 0.5f * (bj.y + bj.w);
    const float wj  = bj.z - bj.x + 1.0f;
    const float hj  = bj.w - bj.y + 1.0f;

    const float pos[4] = {
        logf(fmaxf(fabsf((cxi - cxj) / wi), 1e-3f)) * 100.0f,
        logf(fmaxf(fabsf((cyi - cyj) / hi), 1e-3f)) * 100.0f,
        logf(wi / wj) * 100.0f,
        logf(hi / hj) * 100.0f
    };
    const float dim[8] = {1.0f, 0.421696503f, 0.177827941f, 0.0749894209f,
                          0.0316227766f, 0.0133352143f, 0.00562341325f, 0.00237137371f};

    float sv[32], cv[32];
#pragma unroll
    for (int p = 0; p < 4; ++p)
#pragma unroll
        for (int q = 0; q < 8; ++q)
            __sincosf(pos[p] * dim[q], &sv[p * 8 + q], &cv[p * 8 + q]);

    __syncthreads();
#pragma unroll
    for (int h = 0; h < 8; ++h) {
        float acc = sbg[h];
        const float* wrow = &sWg[h * 64];
#pragma unroll
        for (int g = 0; g < 32; ++g)
            acc = fmaf(sv[g], wrow[g], fmaf(cv[g], wrow[32 + g], acc));
        const float rel = fmaxf(acc, 0.0f);
        lb[(((size_t)b * H_ + h) * N_ + i) * N_ + j] = logf(fmaxf(rel, 1e-6f));
    }
}

// ---------------------------------------------------------------------------
// MFMA flash attention. Block = (b*H+h, q-half): 128 queries, 4 waves x 32 q.
// Q in registers; K staged padded; V staged transposed; online softmax;
// P through per-wave LDS -> PV MFMA. Writes bf16 ao in [B, N, H, DK] layout.
// ---------------------------------------------------------------------------
__global__ __launch_bounds__(256)
void attn_mfma_kernel(const u16* __restrict__ qp, const u16* __restrict__ kp,
                      const u16* __restrict__ vp, const float* __restrict__ lb,
                      u16* __restrict__ ao)
{
    __shared__ __align__(16) u16 Ks[32][136];    // keys x dk, +16B pad per row
    __shared__ __align__(16) u16 Vt[128][40];    // dk x keys (transposed), +pad
    __shared__ __align__(16) u16 Ps[4][32][40];  // per-wave P tile

    const int tid  = threadIdx.x;
    const int lane = tid & 63;
    const int w    = tid >> 6;
    const int l15  = lane & 15;
    const int l4   = lane >> 4;
    const int bh   = blockIdx.x >> 1;
    const int qt   = blockIdx.x & 1;
    const int q0   = qt * 128 + w * 32;   // wave's first query row

    // Q fragments (A-operand): row = lane&15, k = (lane>>4)*8+j
    s8v qf[2][4];
    const u16* qb = qp + ((size_t)bh * N_ + q0) * DK_;
#pragma unroll
    for (int mf = 0; mf < 2; ++mf)
#pragma unroll
        for (int ks = 0; ks < 4; ++ks)
            qf[mf][ks] = *(const s8v*)(qb + (size_t)(mf * 16 + l15) * DK_ + ks * 32 + l4 * 8);

    f4v o[2][8] = {};
    float m_r[2][4], l_r[2][4];
#pragma unroll
    for (int mf = 0; mf < 2; ++mf)
#pragma unroll
        for (int r = 0; r < 4; ++r) { m_r[mf][r] = -INFINITY; l_r[mf][r] = 0.0f; }

    const float scale = 0.08838834764831845f;    // 1/sqrt(128)
    const float* lbb = lb + ((size_t)bh * N_ + q0) * N_;

    const int sr = tid >> 3;          // staging row 0..31
    const int sc = (tid & 7) * 16;    // staging col base

    for (int kt = 0; kt < 8; ++kt) {
        __syncthreads();   // previous tile's LDS reads done
        // stage K [32][128] -> Ks (padded rows)
        {
            const u16* ksrc = kp + ((size_t)bh * N_ + kt * 32) * DK_;
            *(s8v*)&Ks[sr][sc]     = *(const s8v*)(ksrc + (size_t)sr * DK_ + sc);
            *(s8v*)&Ks[sr][sc + 8] = *(const s8v*)(ksrc + (size_t)sr * DK_ + sc + 8);
        }
        // stage V [32][128] transposed -> Vt[d][k]
        {
            const u16* vsrc = vp + ((size_t)bh * N_ + kt * 32) * DK_;
            const s8v v0 = *(const s8v*)(vsrc + (size_t)sr * DK_ + sc);
            const s8v v1 = *(const s8v*)(vsrc + (size_t)sr * DK_ + sc + 8);
#pragma unroll
            for (int jj = 0; jj < 8; ++jj) {
                Vt[sc + jj][sr]     = (u16)v0[jj];
                Vt[sc + 8 + jj][sr] = (u16)v1[jj];
            }
        }
        __syncthreads();

        // ---- S = Q K^T ----
        f4v s[2][2] = {};
#pragma unroll
        for (int ks = 0; ks < 4; ++ks) {
#pragma unroll
            for (int kf = 0; kf < 2; ++kf) {
                const s8v kb = *(const s8v*)&Ks[kf * 16 + l15][ks * 32 + l4 * 8];
#pragma unroll
                for (int mf = 0; mf < 2; ++mf)
                    s[mf][kf] = __builtin_amdgcn_mfma_f32_16x16x32_bf16(
                        qf[mf][ks], kb, s[mf][kf], 0, 0, 0);
            }
        }
        // logits = s*scale + lb
#pragma unroll
        for (int mf = 0; mf < 2; ++mf)
#pragma unroll
            for (int kf = 0; kf < 2; ++kf)
#pragma unroll
                for (int r = 0; r < 4; ++r)
                    s[mf][kf][r] = fmaf(s[mf][kf][r], scale,
                        lbb[(size_t)(mf * 16 + l4 * 4 + r) * N_ + kt * 32 + kf * 16 + l15]);

        // ---- online softmax (row = (lane>>4)*4 + r within 16-row frag) ----
#pragma unroll
        for (int mf = 0; mf < 2; ++mf) {
            float rm[4], al[4];
#pragma unroll
            for (int r = 0; r < 4; ++r) rm[r] = fmaxf(s[mf][0][r], s[mf][1][r]);
#pragma unroll
            for (int st = 1; st <= 8; st <<= 1)
#pragma unroll
                for (int r = 0; r < 4; ++r) rm[r] = fmaxf(rm[r], __shfl_xor(rm[r], st));
#pragma unroll
            for (int r = 0; r < 4; ++r) {
                const float mn = fmaxf(m_r[mf][r], rm[r]);
                al[r] = __expf(m_r[mf][r] - mn);
                m_r[mf][r] = mn;
            }
            float p0[4], p1[4], rs[4];
#pragma unroll
            for (int r = 0; r < 4; ++r) {
                p0[r] = __expf(s[mf][0][r] - m_r[mf][r]);
                p1[r] = __expf(s[mf][1][r] - m_r[mf][r]);
                rs[r] = p0[r] + p1[r];
            }
#pragma unroll
            for (int st = 1; st <= 8; st <<= 1)
#pragma unroll
                for (int r = 0; r < 4; ++r) rs[r] += __shfl_xor(rs[r], st);
#pragma unroll
            for (int r = 0; r < 4; ++r) {
                l_r[mf][r] = l_r[mf][r] * al[r] + rs[r];
                Ps[w][mf * 16 + l4 * 4 + r][l15]      = f2b(p0[r]);
                Ps[w][mf * 16 + l4 * 4 + r][16 + l15] = f2b(p1[r]);
            }
#pragma unroll
            for (int nf = 0; nf < 8; ++nf)
#pragma unroll
                for (int r = 0; r < 4; ++r) o[mf][nf][r] *= al[r];
        }

        // ---- O += P V (A = P from per-wave LDS, B = Vt) ----
        s8v pa[2];
#pragma unroll
        for (int mf = 0; mf < 2; ++mf)
            pa[mf] = *(const s8v*)&Ps[w][mf * 16 + l15][l4 * 8];
#pragma unroll
        for (int nf = 0; nf < 8; ++nf) {
            const s8v vb = *(const s8v*)&Vt[nf * 16 + l15][l4 * 8];
#pragma unroll
            for (int mf = 0; mf < 2; ++mf)
                o[mf][nf] = __builtin_amdgcn_mfma_f32_16x16x32_bf16(
                    pa[mf], vb, o[mf][nf], 0, 0, 0);
        }
    }

    // ---- epilogue: normalize, write bf16 to ao[B, N, H, DK] ----
    const int b = bh >> 3, h = bh & 7;
#pragma unroll
    for (int mf = 0; mf < 2; ++mf) {
        float inv[4];
#pragma unroll
        for (int r = 0; r < 4; ++r) inv[r] = 1.0f / l_r[mf][r];
#pragma unroll
        for (int nf = 0; nf < 8; ++nf) {
#pragma unroll
            for (int r = 0; r < 4; ++r) {
                const int tok = q0 + mf * 16 + l4 * 4 + r;
                const int d = nf * 16 + l15;
                ao[(((size_t)b * N_ + tok) * H_ + h) * DK_ + d] = f2b(o[mf][nf][r] * inv[r]);
            }
        }
    }
}

// ---------------------------------------------------------------------------
// Workspace (96 MiB total):
//   xb  : 3 x 4M bf16   = 24 MiB  (xq, xk, xv converted)
//   Wt  : 4 x 1M bf16   =  8 MiB  (Wq, Wk, Wv, Wo transposed)
//   qkv : 3 x 4M bf16   = 24 MiB  (q, k, v projected, [B,H,N,DK])
//   lb  : 8M fp32       = 32 MiB  (log attention bias [B,H,N,N])
//   ao  : 4M bf16       =  8 MiB  (attention out, [B,N,H,DK])
// ---------------------------------------------------------------------------
extern "C" void kernel_launch(void* const* d_in, const int* in_sizes, int n_in,
                              void* d_out, int out_size, void* d_ws, size_t ws_size,
                              hipStream_t stream)
{
    const float* xq = (const float*)d_in[0];
    const float* xk = (const float*)d_in[1];
    const float* xv = (const float*)d_in[2];
    const float* fg = (const float*)d_in[3];
    const float* Wq = (const float*)d_in[4];
    const float* bq = (const float*)d_in[5];
    const float* Wk = (const float*)d_in[6];
    const float* bk = (const float*)d_in[7];
    const float* Wv = (const float*)d_in[8];
    const float* bv = (const float*)d_in[9];
    const float* Wg = (const float*)d_in[10];
    const float* bg = (const float*)d_in[11];
    const float* Wo = (const float*)d_in[12];
    const float* bo = (const float*)d_in[13];

    char* w8 = (char*)d_ws;
    u16*   xb  = (u16*)(w8);
    u16*   Wt  = (u16*)(w8 + 25165824);
    u16*   qkv = (u16*)(w8 + 33554432);
    float* lb  = (float*)(w8 + 58720256);
    u16*   ao  = (u16*)(w8 + 92274688);

    const int n8 = (B_ * N_ * D_) / 8;   // 524288
    cvt_kernel<<<n8 / 256, 256, 0, stream>>>(xq, xb, n8);
    cvt_kernel<<<n8 / 256, 256, 0, stream>>>(xk, xb + 4194304, n8);
    cvt_kernel<<<n8 / 256, 256, 0, stream>>>(xv, xb + 2 * 4194304, n8);
    cvtT_kernel<<<dim3(32, 32, 4), 256, 0, stream>>>(Wq, Wk, Wv, Wo, Wt);

    gemm_kernel<<<dim3(8, 64, 3), 256, 0, stream>>>(xb, Wt, bq, bk, bv, qkv, 1);

    boxbias_kernel<<<B_ * N_, 256, 0, stream>>>(fg, Wg, bg, lb);

    attn_mfma_kernel<<<B_ * H_ * 2, 256, 0, stream>>>(
        qkv, qkv + 4194304, qkv + 2 * 4194304, lb, ao);

    gemm_kernel<<<dim3(8, 64, 1), 256, 0, stream>>>(
        ao, Wt + 3 * 1048576, bo, bo, bo, d_out, 0);
}